// Round 1
// baseline (367.081 us; speedup 1.0000x reference)
//
#include <hip/hip_runtime.h>
#include <math.h>

// FHN dynamics: row-wise max-abs normalization + sigmoid gating + 8 IMEX steps.
// One block per 2048-element row; fully register-resident per thread (8 elems).

#define ROWLEN 2048
#define BLOCK  256
#define EPT    8                 // elements per thread
#define F4PT   (EPT / 4)         // float4 loads per thread = 2

__global__ __launch_bounds__(BLOCK)
void fhn_kernel(const float* __restrict__ stim,
                const float* __restrict__ a_p,
                const float* __restrict__ b_p,
                const float* __restrict__ dt_p,
                const int*   __restrict__ nsteps_p,
                float* __restrict__ out,      // [n_elem] response, then [n_elem] v
                long long n_elem)
{
    const long long row = blockIdx.x;
    const float* __restrict__ srow = stim + row * ROWLEN;
    float* __restrict__ rrow = out + row * ROWLEN;
    float* __restrict__ vrow = out + n_elem + row * ROWLEN;

    const int tid = threadIdx.x;

    // ---- coalesced float4 loads: lane t takes float4 slots {t, t+256} ----
    float s[EPT];
    #pragma unroll
    for (int i = 0; i < F4PT; ++i) {
        float4 f = reinterpret_cast<const float4*>(srow)[tid + i * BLOCK];
        s[4*i+0] = f.x; s[4*i+1] = f.y; s[4*i+2] = f.z; s[4*i+3] = f.w;
    }

    // ---- row max(|s|): local -> wave shuffle -> cross-wave via LDS ----
    float m = 0.0f;
    #pragma unroll
    for (int e = 0; e < EPT; ++e) m = fmaxf(m, fabsf(s[e]));
    #pragma unroll
    for (int off = 32; off > 0; off >>= 1)
        m = fmaxf(m, __shfl_down(m, off, 64));
    __shared__ float smax[BLOCK / 64];
    if ((tid & 63) == 0) smax[tid >> 6] = m;
    __syncthreads();
    m = fmaxf(fmaxf(smax[0], smax[1]), fmaxf(smax[2], smax[3]));

    const float scale     = fmaxf(m, 1e-6f);
    const float inv_scale = 1.0f / scale;

    // ---- scalar params (device-resident 1-element arrays) ----
    const float a  = *a_p;
    const float b  = *b_p;
    const float dt = *dt_p;
    const int   n_steps = *nsteps_p;
    const float alpha     = dt / 12.5f;             // TAU = 12.5
    const float inv_denom = 1.0f / (1.0f + alpha * b);

    // ---- conditioned input current I ----
    float I[EPT], v[EPT], w[EPT];
    #pragma unroll
    for (int e = 0; e < EPT; ++e) {
        const float as   = fabsf(s[e]);
        const float gate = 1.0f / (1.0f + __expf(-(as - 0.5f) * 10.0f));
        I[e] = s[e] * inv_scale * (0.1f + 0.9f * gate);
        v[e] = 0.0f;
        w[e] = 0.0f;
    }

    // ---- IMEX FHN steps ----
    for (int n = 0; n < n_steps; ++n) {
        #pragma unroll
        for (int e = 0; e < EPT; ++e) {
            const float ve = v[e];
            const float dv = ve - ve * ve * ve * (1.0f / 3.0f) - w[e] + I[e];
            const float vn = ve + dt * dv;
            const float wn = (w[e] + alpha * (vn + a)) * inv_denom;
            v[e] = fminf(fmaxf(vn, -3.0f), 3.0f);
            w[e] = fminf(fmaxf(wn, -3.0f), 3.0f);
        }
    }

    // ---- epilogue: response = v * scale; also emit v ----
    #pragma unroll
    for (int i = 0; i < F4PT; ++i) {
        float4 r, vv;
        r.x  = v[4*i+0] * scale; r.y  = v[4*i+1] * scale;
        r.z  = v[4*i+2] * scale; r.w  = v[4*i+3] * scale;
        vv.x = v[4*i+0];         vv.y = v[4*i+1];
        vv.z = v[4*i+2];         vv.w = v[4*i+3];
        reinterpret_cast<float4*>(rrow)[tid + i * BLOCK] = r;
        reinterpret_cast<float4*>(vrow)[tid + i * BLOCK] = vv;
    }
}

extern "C" void kernel_launch(void* const* d_in, const int* in_sizes, int n_in,
                              void* d_out, int out_size, void* d_ws, size_t ws_size,
                              hipStream_t stream) {
    const float* stim = (const float*)d_in[0];
    const float* a_p  = (const float*)d_in[1];
    const float* b_p  = (const float*)d_in[2];
    const float* dt_p = (const float*)d_in[3];
    const int*   n_p  = (const int*)d_in[4];
    float* out = (float*)d_out;

    const long long n_elem = (long long)in_sizes[0];
    const int rows = (int)(n_elem / ROWLEN);

    fhn_kernel<<<rows, BLOCK, 0, stream>>>(stim, a_p, b_p, dt_p, n_p, out, n_elem);
}